// Round 1
// baseline (541.127 us; speedup 1.0000x reference)
//
#include <hip/hip_runtime.h>
#include <math.h>

namespace {

constexpr int NN = 20000;   // nodes
constexpr int NE = 400000;  // edges

constexpr float RS8   = 0.35355339059327373f;  // 1/sqrt(8)
constexpr float RS128 = 0.08838834764831845f;  // 1/sqrt(128)

__device__ __forceinline__ float silu_f(float x) {
    return x / (1.0f + __expf(-x));
}

// ---------------- node kernel: sc, nf, q ----------------
__global__ __launch_bounds__(256) void node_kernel(
    const float* __restrict__ node_input, const float* __restrict__ node_attr,
    const float* __restrict__ W_sc, const float* __restrict__ W_lin1,
    const float* __restrict__ W_hq,
    float* __restrict__ nf_out, float* __restrict__ q_out, float* __restrict__ sc_out)
{
    __shared__ float sWsc[2048];   // [a][b][c] (16,8,16), scale folded
    __shared__ float sW1[256];     // [a][c] (16,16)
    __shared__ float sWq[128];     // [a][c] (16,8)
    for (int i = threadIdx.x; i < 2048; i += 256) sWsc[i] = W_sc[i] * RS128;
    if (threadIdx.x < 256) sW1[threadIdx.x] = W_lin1[threadIdx.x] * 0.25f;
    if (threadIdx.x < 128) sWq[threadIdx.x] = W_hq[threadIdx.x] * 0.25f;
    __syncthreads();

    int n = blockIdx.x * 256 + threadIdx.x;
    if (n >= NN) return;

    float ni[16], na[8];
    {
        const float4* p = (const float4*)(node_input + (size_t)n * 16);
        #pragma unroll
        for (int j = 0; j < 4; ++j) {
            float4 t = p[j];
            ni[4*j+0]=t.x; ni[4*j+1]=t.y; ni[4*j+2]=t.z; ni[4*j+3]=t.w;
        }
        const float4* pa = (const float4*)(node_attr + (size_t)n * 8);
        #pragma unroll
        for (int j = 0; j < 2; ++j) {
            float4 t = pa[j];
            na[4*j+0]=t.x; na[4*j+1]=t.y; na[4*j+2]=t.z; na[4*j+3]=t.w;
        }
    }

    float sc[16];
    #pragma unroll
    for (int c = 0; c < 16; ++c) sc[c] = 0.f;
    #pragma unroll 4
    for (int a = 0; a < 16; ++a) {
        #pragma unroll
        for (int b = 0; b < 8; ++b) {
            float p = ni[a] * na[b];
            const float* w = &sWsc[(a * 8 + b) * 16];
            #pragma unroll
            for (int c = 0; c < 16; ++c) sc[c] += p * w[c];
        }
    }

    float nf[16];
    #pragma unroll
    for (int c = 0; c < 16; ++c) {
        float t = 0.f;
        #pragma unroll
        for (int a = 0; a < 16; ++a) t += ni[a] * sW1[a * 16 + c];
        nf[c] = t;
    }
    float q[8];
    #pragma unroll
    for (int c = 0; c < 8; ++c) {
        float t = 0.f;
        #pragma unroll
        for (int a = 0; a < 16; ++a) t += nf[a] * sWq[a * 8 + c];
        q[c] = t;
    }

    float4* nfo = (float4*)(nf_out + (size_t)n * 16);
    #pragma unroll
    for (int j = 0; j < 4; ++j) nfo[j] = make_float4(nf[4*j], nf[4*j+1], nf[4*j+2], nf[4*j+3]);
    float4* qo = (float4*)(q_out + (size_t)n * 8);
    #pragma unroll
    for (int j = 0; j < 2; ++j) qo[j] = make_float4(q[4*j], q[4*j+1], q[4*j+2], q[4*j+3]);
    float4* sco = (float4*)(sc_out + (size_t)n * 16);
    #pragma unroll
    for (int j = 0; j < 4; ++j) sco[j] = make_float4(sc[4*j], sc[4*j+1], sc[4*j+2], sc[4*j+3]);
}

__device__ __forceinline__ void mlp_hidden(const float es[16], const float* __restrict__ w0,
                                           const float* __restrict__ w1, const float* __restrict__ w2,
                                           float out[8])
{
    float h0[8];
    #pragma unroll
    for (int j = 0; j < 8; ++j) {
        float t = 0.f;
        #pragma unroll
        for (int i = 0; i < 16; ++i) t += es[i] * w0[i * 8 + j];
        h0[j] = silu_f(t);
    }
    float h1[8];
    #pragma unroll
    for (int j = 0; j < 8; ++j) {
        float t = 0.f;
        #pragma unroll
        for (int i = 0; i < 8; ++i) t += h0[i] * w1[i * 8 + j];
        h1[j] = silu_f(t);
    }
    #pragma unroll
    for (int j = 0; j < 8; ++j) {
        float t = 0.f;
        #pragma unroll
        for (int i = 0; i < 8; ++i) t += h1[i] * w2[i * 8 + j];
        out[j] = silu_f(t);
    }
}

// ---------------- edge kernel: k, v, x, ex, z ----------------
__global__ __launch_bounds__(256) void edge_kernel(
    const float* __restrict__ nf, const float* __restrict__ q,
    const int* __restrict__ edge_src, const int* __restrict__ edge_dst,
    const float* __restrict__ edge_attr, const float* __restrict__ edge_scalars,
    const float* __restrict__ fck_w0, const float* __restrict__ fck_w1,
    const float* __restrict__ fck_w2, const float* __restrict__ fck_w3,
    const float* __restrict__ fcv_w0, const float* __restrict__ fcv_w1,
    const float* __restrict__ fcv_w2, const float* __restrict__ fcv_w3,
    const float* __restrict__ W_dot,
    float* __restrict__ ex_out, float* __restrict__ v_out, float* __restrict__ z)
{
    __shared__ float sk0[128], sk1[64], sk2[64], sk3[4096];
    __shared__ float sv0[128], sv1[64], sv2[64], sv3[512];
    __shared__ float sdot[64];
    int tid = threadIdx.x;
    for (int i = tid; i < 128; i += 256) sk0[i] = fck_w0[i] * 0.25f;
    for (int i = tid; i < 64;  i += 256) sk1[i] = fck_w1[i] * RS8;
    for (int i = tid; i < 64;  i += 256) sk2[i] = fck_w2[i] * RS8;
    for (int i = tid; i < 4096; i += 256) sk3[i] = fck_w3[i] * (RS8 * 0.125f);  // * 1/sqrt(64)
    for (int i = tid; i < 128; i += 256) sv0[i] = fcv_w0[i] * 0.25f;
    for (int i = tid; i < 64;  i += 256) sv1[i] = fcv_w1[i] * RS8;
    for (int i = tid; i < 64;  i += 256) sv2[i] = fcv_w2[i] * RS8;
    for (int i = tid; i < 512; i += 256) sv3[i] = fcv_w3[i] * (RS8 * 0.5f);     // * 1/sqrt(4)
    for (int i = tid; i < 64;  i += 256) sdot[i] = W_dot[i] * 0.125f;           // * 1/sqrt(64)
    __syncthreads();

    int e = blockIdx.x * 256 + tid;
    if (e >= NE) return;

    float es[16];
    {
        const float4* p = (const float4*)(edge_scalars + (size_t)e * 16);
        #pragma unroll
        for (int j = 0; j < 4; ++j) {
            float4 t = p[j];
            es[4*j+0]=t.x; es[4*j+1]=t.y; es[4*j+2]=t.z; es[4*j+3]=t.w;
        }
    }

    float hk[8], hv[8];
    mlp_hidden(es, sk0, sk1, sk2, hk);
    mlp_hidden(es, sv0, sv1, sv2, hv);

    int src = edge_src[e];
    int dst = edge_dst[e];

    float sf[16];
    {
        const float4* p = (const float4*)(nf + (size_t)src * 16);
        #pragma unroll
        for (int j = 0; j < 4; ++j) {
            float4 t = p[j];
            sf[4*j+0]=t.x; sf[4*j+1]=t.y; sf[4*j+2]=t.z; sf[4*j+3]=t.w;
        }
    }
    float ea[4];
    {
        float4 t = *(const float4*)(edge_attr + (size_t)e * 4);
        ea[0]=t.x; ea[1]=t.y; ea[2]=t.z; ea[3]=t.w;
    }

    // k[c] = sum_{h,u,v} hk[h] * sk3[h][u*32+v*8+c] * sf[u] * ea[v]
    float k[8];
    #pragma unroll
    for (int c = 0; c < 8; ++c) k[c] = 0.f;
    #pragma unroll 2
    for (int h = 0; h < 8; ++h) {
        float hh = hk[h];
        const float* wrow = sk3 + h * 512;
        #pragma unroll
        for (int u = 0; u < 16; ++u) {
            float a = hh * sf[u];
            #pragma unroll
            for (int v = 0; v < 4; ++v) {
                float b = a * ea[v];
                const float* wp = wrow + u * 32 + v * 8;
                #pragma unroll
                for (int c = 0; c < 8; ++c) k[c] += b * wp[c];
            }
        }
    }

    // v[u] = sf[u] * sum_{h,w} hv[h] * sv3[h][u*4+w] * ea[w]
    float hea[8][4];
    #pragma unroll
    for (int h = 0; h < 8; ++h)
        #pragma unroll
        for (int w = 0; w < 4; ++w) hea[h][w] = hv[h] * ea[w];
    float vv[16];
    #pragma unroll
    for (int u = 0; u < 16; ++u) {
        float t = 0.f;
        #pragma unroll
        for (int h = 0; h < 8; ++h)
            #pragma unroll
            for (int w = 0; w < 4; ++w) t += hea[h][w] * sv3[h * 64 + u * 4 + w];
        vv[u] = sf[u] * t;
    }

    // x = sum_{a,b} q[dst][a] * k[b] * Wdot[a][b]
    float qd[8];
    {
        const float4* p = (const float4*)(q + (size_t)dst * 8);
        #pragma unroll
        for (int j = 0; j < 2; ++j) {
            float4 t = p[j];
            qd[4*j+0]=t.x; qd[4*j+1]=t.y; qd[4*j+2]=t.z; qd[4*j+3]=t.w;
        }
    }
    float x = 0.f;
    #pragma unroll
    for (int a = 0; a < 8; ++a) {
        float t = 0.f;
        #pragma unroll
        for (int b = 0; b < 8; ++b) t += k[b] * sdot[a * 8 + b];
        x += qd[a] * t;
    }

    // softmax is invariant to the global max shift; |x| is O(few) so exp(x) is safe in f32
    float exv = __expf(x);
    ex_out[e] = exv;
    atomicAdd(&z[dst], exv);

    float4* vo = (float4*)(v_out + (size_t)e * 16);
    #pragma unroll
    for (int j = 0; j < 4; ++j) vo[j] = make_float4(vv[4*j], vv[4*j+1], vv[4*j+2], vv[4*j+3]);
}

// ---------------- scatter kernel: agg += alpha * v ----------------
__global__ __launch_bounds__(256) void scatter_kernel(
    const int* __restrict__ edge_dst, const float* __restrict__ ex,
    const float* __restrict__ z, const float* __restrict__ v_in,
    float* __restrict__ agg)
{
    int e = blockIdx.x * 256 + threadIdx.x;
    if (e >= NE) return;
    int dst = edge_dst[e];
    float zz = z[dst];
    float alpha = ex[e] / (zz == 0.f ? 1.f : zz);
    const float4* pv = (const float4*)(v_in + (size_t)e * 16);
    float* ap = agg + (size_t)dst * 16;
    #pragma unroll
    for (int j = 0; j < 4; ++j) {
        float4 t = pv[j];
        atomicAdd(ap + 4*j + 0, alpha * t.x);
        atomicAdd(ap + 4*j + 1, alpha * t.y);
        atomicAdd(ap + 4*j + 2, alpha * t.z);
        atomicAdd(ap + 4*j + 3, alpha * t.w);
    }
}

// ---------------- output kernel: out = sc + agg @ W_lin2' ----------------
__global__ __launch_bounds__(256) void out_kernel(
    const float* __restrict__ sc, const float* __restrict__ agg,
    const float* __restrict__ W_lin2, float* __restrict__ out)
{
    __shared__ float sW[256];
    if (threadIdx.x < 256) sW[threadIdx.x] = W_lin2[threadIdx.x] * 0.25f;
    __syncthreads();
    int n = blockIdx.x * 256 + threadIdx.x;
    if (n >= NN) return;
    float a[16];
    {
        const float4* p = (const float4*)(agg + (size_t)n * 16);
        #pragma unroll
        for (int j = 0; j < 4; ++j) {
            float4 t = p[j];
            a[4*j+0]=t.x; a[4*j+1]=t.y; a[4*j+2]=t.z; a[4*j+3]=t.w;
        }
    }
    const float4* psc = (const float4*)(sc + (size_t)n * 16);
    float4* po = (float4*)(out + (size_t)n * 16);
    #pragma unroll
    for (int j = 0; j < 4; ++j) {
        float4 s = psc[j];
        float o[4];
        #pragma unroll
        for (int cc = 0; cc < 4; ++cc) {
            int c = 4*j + cc;
            float t = 0.f;
            #pragma unroll
            for (int u = 0; u < 16; ++u) t += a[u] * sW[u * 16 + c];
            o[cc] = t;
        }
        po[j] = make_float4(s.x + o[0], s.y + o[1], s.z + o[2], s.w + o[3]);
    }
}

} // namespace

extern "C" void kernel_launch(void* const* d_in, const int* in_sizes, int n_in,
                              void* d_out, int out_size, void* d_ws, size_t ws_size,
                              hipStream_t stream)
{
    const float* node_input   = (const float*)d_in[0];
    const float* node_attr    = (const float*)d_in[1];
    const int*   edge_src     = (const int*)d_in[2];
    const int*   edge_dst     = (const int*)d_in[3];
    const float* edge_attr    = (const float*)d_in[4];
    const float* edge_scalars = (const float*)d_in[5];
    const float* W_sc   = (const float*)d_in[6];
    const float* W_lin1 = (const float*)d_in[7];
    const float* W_hq   = (const float*)d_in[8];
    const float* fck_w0 = (const float*)d_in[9];
    const float* fck_w1 = (const float*)d_in[10];
    const float* fck_w2 = (const float*)d_in[11];
    const float* fck_w3 = (const float*)d_in[12];
    const float* fcv_w0 = (const float*)d_in[13];
    const float* fcv_w1 = (const float*)d_in[14];
    const float* fcv_w2 = (const float*)d_in[15];
    const float* fcv_w3 = (const float*)d_in[16];
    const float* W_dot  = (const float*)d_in[17];
    const float* W_lin2 = (const float*)d_in[18];

    float* ws  = (float*)d_ws;
    float* nf  = ws;                  // NN*16
    float* q   = nf  + (size_t)NN * 16;  // NN*8
    float* sc  = q   + (size_t)NN * 8;   // NN*16
    float* z   = sc  + (size_t)NN * 16;  // NN
    float* agg = z   + NN;               // NN*16
    float* ex  = agg + (size_t)NN * 16;  // NE
    float* vv  = ex  + NE;               // NE*16

    // zero z + agg (contiguous)
    hipMemsetAsync(z, 0, (size_t)(NN + NN * 16) * sizeof(float), stream);

    node_kernel<<<(NN + 255) / 256, 256, 0, stream>>>(
        node_input, node_attr, W_sc, W_lin1, W_hq, nf, q, sc);
    edge_kernel<<<(NE + 255) / 256, 256, 0, stream>>>(
        nf, q, edge_src, edge_dst, edge_attr, edge_scalars,
        fck_w0, fck_w1, fck_w2, fck_w3, fcv_w0, fcv_w1, fcv_w2, fcv_w3,
        W_dot, ex, vv, z);
    scatter_kernel<<<(NE + 255) / 256, 256, 0, stream>>>(edge_dst, ex, z, vv, agg);
    out_kernel<<<(NN + 255) / 256, 256, 0, stream>>>(sc, agg, W_lin2, (float*)d_out);
}

// Round 2
// 254.285 us; speedup vs baseline: 2.1280x; 2.1280x over previous
//
#include <hip/hip_runtime.h>
#include <math.h>

namespace {

constexpr int NN = 20000;   // nodes
constexpr int NE = 400000;  // edges

constexpr float RS8   = 0.35355339059327373f;  // 1/sqrt(8)
constexpr float RS128 = 0.08838834764831845f;  // 1/sqrt(128)

__device__ __forceinline__ float silu_f(float x) {
    return x / (1.0f + __expf(-x));
}

// ---------------- node kernel: sc, nf, q ----------------
__global__ __launch_bounds__(256) void node_kernel(
    const float* __restrict__ node_input, const float* __restrict__ node_attr,
    const float* __restrict__ W_sc, const float* __restrict__ W_lin1,
    const float* __restrict__ W_hq,
    float* __restrict__ nf_out, float* __restrict__ q_out, float* __restrict__ sc_out)
{
    __shared__ float sWsc[2048];   // [a][b][c] (16,8,16), scale folded
    __shared__ float sW1[256];     // [a][c] (16,16)
    __shared__ float sWq[128];     // [a][c] (16,8)
    for (int i = threadIdx.x; i < 2048; i += 256) sWsc[i] = W_sc[i] * RS128;
    if (threadIdx.x < 256) sW1[threadIdx.x] = W_lin1[threadIdx.x] * 0.25f;
    if (threadIdx.x < 128) sWq[threadIdx.x] = W_hq[threadIdx.x] * 0.25f;
    __syncthreads();

    int n = blockIdx.x * 256 + threadIdx.x;
    if (n >= NN) return;

    float ni[16], na[8];
    {
        const float4* p = (const float4*)(node_input + (size_t)n * 16);
        #pragma unroll
        for (int j = 0; j < 4; ++j) {
            float4 t = p[j];
            ni[4*j+0]=t.x; ni[4*j+1]=t.y; ni[4*j+2]=t.z; ni[4*j+3]=t.w;
        }
        const float4* pa = (const float4*)(node_attr + (size_t)n * 8);
        #pragma unroll
        for (int j = 0; j < 2; ++j) {
            float4 t = pa[j];
            na[4*j+0]=t.x; na[4*j+1]=t.y; na[4*j+2]=t.z; na[4*j+3]=t.w;
        }
    }

    float sc[16];
    #pragma unroll
    for (int c = 0; c < 16; ++c) sc[c] = 0.f;
    #pragma unroll 4
    for (int a = 0; a < 16; ++a) {
        #pragma unroll
        for (int b = 0; b < 8; ++b) {
            float p = ni[a] * na[b];
            const float* w = &sWsc[(a * 8 + b) * 16];
            #pragma unroll
            for (int c = 0; c < 16; ++c) sc[c] += p * w[c];
        }
    }

    float nf[16];
    #pragma unroll
    for (int c = 0; c < 16; ++c) {
        float t = 0.f;
        #pragma unroll
        for (int a = 0; a < 16; ++a) t += ni[a] * sW1[a * 16 + c];
        nf[c] = t;
    }
    float q[8];
    #pragma unroll
    for (int c = 0; c < 8; ++c) {
        float t = 0.f;
        #pragma unroll
        for (int a = 0; a < 16; ++a) t += nf[a] * sWq[a * 8 + c];
        q[c] = t;
    }

    float4* nfo = (float4*)(nf_out + (size_t)n * 16);
    #pragma unroll
    for (int j = 0; j < 4; ++j) nfo[j] = make_float4(nf[4*j], nf[4*j+1], nf[4*j+2], nf[4*j+3]);
    float4* qo = (float4*)(q_out + (size_t)n * 8);
    #pragma unroll
    for (int j = 0; j < 2; ++j) qo[j] = make_float4(q[4*j], q[4*j+1], q[4*j+2], q[4*j+3]);
    float4* sco = (float4*)(sc_out + (size_t)n * 16);
    #pragma unroll
    for (int j = 0; j < 4; ++j) sco[j] = make_float4(sc[4*j], sc[4*j+1], sc[4*j+2], sc[4*j+3]);
}

__device__ __forceinline__ void mlp_hidden(const float es[16], const float* __restrict__ w0,
                                           const float* __restrict__ w1, const float* __restrict__ w2,
                                           float out[8])
{
    float h0[8];
    #pragma unroll
    for (int j = 0; j < 8; ++j) {
        float t = 0.f;
        #pragma unroll
        for (int i = 0; i < 16; ++i) t += es[i] * w0[i * 8 + j];
        h0[j] = silu_f(t);
    }
    float h1[8];
    #pragma unroll
    for (int j = 0; j < 8; ++j) {
        float t = 0.f;
        #pragma unroll
        for (int i = 0; i < 8; ++i) t += h0[i] * w1[i * 8 + j];
        h1[j] = silu_f(t);
    }
    #pragma unroll
    for (int j = 0; j < 8; ++j) {
        float t = 0.f;
        #pragma unroll
        for (int i = 0; i < 8; ++i) t += h1[i] * w2[i * 8 + j];
        out[j] = silu_f(t);
    }
}

// ---------------- edge kernel: k, v, x, ex + dst histogram ----------------
__global__ __launch_bounds__(256) void edge_kernel(
    const float* __restrict__ nf, const float* __restrict__ q,
    const int* __restrict__ edge_src, const int* __restrict__ edge_dst,
    const float* __restrict__ edge_attr, const float* __restrict__ edge_scalars,
    const float* __restrict__ fck_w0, const float* __restrict__ fck_w1,
    const float* __restrict__ fck_w2, const float* __restrict__ fck_w3,
    const float* __restrict__ fcv_w0, const float* __restrict__ fcv_w1,
    const float* __restrict__ fcv_w2, const float* __restrict__ fcv_w3,
    const float* __restrict__ W_dot,
    float* __restrict__ ex_out, float* __restrict__ v_out, int* __restrict__ counts)
{
    __shared__ float sk0[128], sk1[64], sk2[64], sk3[4096];
    __shared__ float sv0[128], sv1[64], sv2[64], sv3[512];
    __shared__ float sdot[64];
    int tid = threadIdx.x;
    for (int i = tid; i < 128; i += 256) sk0[i] = fck_w0[i] * 0.25f;
    for (int i = tid; i < 64;  i += 256) sk1[i] = fck_w1[i] * RS8;
    for (int i = tid; i < 64;  i += 256) sk2[i] = fck_w2[i] * RS8;
    for (int i = tid; i < 4096; i += 256) sk3[i] = fck_w3[i] * (RS8 * 0.125f);  // * 1/sqrt(64)
    for (int i = tid; i < 128; i += 256) sv0[i] = fcv_w0[i] * 0.25f;
    for (int i = tid; i < 64;  i += 256) sv1[i] = fcv_w1[i] * RS8;
    for (int i = tid; i < 64;  i += 256) sv2[i] = fcv_w2[i] * RS8;
    for (int i = tid; i < 512; i += 256) sv3[i] = fcv_w3[i] * (RS8 * 0.5f);     // * 1/sqrt(4)
    for (int i = tid; i < 64;  i += 256) sdot[i] = W_dot[i] * 0.125f;           // * 1/sqrt(64)
    __syncthreads();

    int e = blockIdx.x * 256 + tid;
    if (e >= NE) return;

    float es[16];
    {
        const float4* p = (const float4*)(edge_scalars + (size_t)e * 16);
        #pragma unroll
        for (int j = 0; j < 4; ++j) {
            float4 t = p[j];
            es[4*j+0]=t.x; es[4*j+1]=t.y; es[4*j+2]=t.z; es[4*j+3]=t.w;
        }
    }

    float hk[8], hv[8];
    mlp_hidden(es, sk0, sk1, sk2, hk);
    mlp_hidden(es, sv0, sv1, sv2, hv);

    int src = edge_src[e];
    int dst = edge_dst[e];
    atomicAdd(&counts[dst], 1);   // CSR histogram (fused)

    float sf[16];
    {
        const float4* p = (const float4*)(nf + (size_t)src * 16);
        #pragma unroll
        for (int j = 0; j < 4; ++j) {
            float4 t = p[j];
            sf[4*j+0]=t.x; sf[4*j+1]=t.y; sf[4*j+2]=t.z; sf[4*j+3]=t.w;
        }
    }
    float ea[4];
    {
        float4 t = *(const float4*)(edge_attr + (size_t)e * 4);
        ea[0]=t.x; ea[1]=t.y; ea[2]=t.z; ea[3]=t.w;
    }

    // k[c] = sum_{h,u,v} hk[h] * sk3[h][u*32+v*8+c] * sf[u] * ea[v]
    float k[8];
    #pragma unroll
    for (int c = 0; c < 8; ++c) k[c] = 0.f;
    #pragma unroll 2
    for (int h = 0; h < 8; ++h) {
        float hh = hk[h];
        const float* wrow = sk3 + h * 512;
        #pragma unroll
        for (int u = 0; u < 16; ++u) {
            float a = hh * sf[u];
            #pragma unroll
            for (int v = 0; v < 4; ++v) {
                float b = a * ea[v];
                const float* wp = wrow + u * 32 + v * 8;
                #pragma unroll
                for (int c = 0; c < 8; ++c) k[c] += b * wp[c];
            }
        }
    }

    // v[u] = sf[u] * sum_{h,w} hv[h] * sv3[h][u*4+w] * ea[w]
    float hea[8][4];
    #pragma unroll
    for (int h = 0; h < 8; ++h)
        #pragma unroll
        for (int w = 0; w < 4; ++w) hea[h][w] = hv[h] * ea[w];
    float vv[16];
    #pragma unroll
    for (int u = 0; u < 16; ++u) {
        float t = 0.f;
        #pragma unroll
        for (int h = 0; h < 8; ++h)
            #pragma unroll
            for (int w = 0; w < 4; ++w) t += hea[h][w] * sv3[h * 64 + u * 4 + w];
        vv[u] = sf[u] * t;
    }

    // x = sum_{a,b} q[dst][a] * k[b] * Wdot[a][b]
    float qd[8];
    {
        const float4* p = (const float4*)(q + (size_t)dst * 8);
        #pragma unroll
        for (int j = 0; j < 2; ++j) {
            float4 t = p[j];
            qd[4*j+0]=t.x; qd[4*j+1]=t.y; qd[4*j+2]=t.z; qd[4*j+3]=t.w;
        }
    }
    float x = 0.f;
    #pragma unroll
    for (int a = 0; a < 8; ++a) {
        float t = 0.f;
        #pragma unroll
        for (int b = 0; b < 8; ++b) t += k[b] * sdot[a * 8 + b];
        x += qd[a] * t;
    }

    // softmax is invariant to the global max shift; |x| is O(few) so exp(x) is safe in f32
    ex_out[e] = __expf(x);

    float4* vo = (float4*)(v_out + (size_t)e * 16);
    #pragma unroll
    for (int j = 0; j < 4; ++j) vo[j] = make_float4(vv[4*j], vv[4*j+1], vv[4*j+2], vv[4*j+3]);
}

// ---------------- scan kernel: exclusive prefix of counts -> offs ----------------
// single block, 1024 threads, 20 elements per thread (20480 >= NN)
__global__ __launch_bounds__(1024) void scan_kernel(
    const int* __restrict__ counts, int* __restrict__ offs)
{
    __shared__ int part[1024];
    int t = threadIdx.x;
    int base = t * 20;
    int s = 0;
    #pragma unroll 4
    for (int i = 0; i < 20; ++i) {
        int idx = base + i;
        if (idx < NN) s += counts[idx];
    }
    part[t] = s;
    __syncthreads();
    #pragma unroll
    for (int d = 1; d < 1024; d <<= 1) {
        int v = (t >= d) ? part[t - d] : 0;
        __syncthreads();
        part[t] += v;
        __syncthreads();
    }
    int run = part[t] - s;   // exclusive base for this chunk
    for (int i = 0; i < 20; ++i) {
        int idx = base + i;
        if (idx < NN) {
            offs[idx] = run;
            run += counts[idx];
        }
    }
}

// ---------------- placement: offs[dst]++ assigns slots; offs becomes inclusive ----------------
__global__ __launch_bounds__(256) void place_kernel(
    const int* __restrict__ edge_dst, int* __restrict__ offs, int* __restrict__ eids)
{
    int e = blockIdx.x * 256 + threadIdx.x;
    if (e >= NE) return;
    int dst = edge_dst[e];
    int pos = atomicAdd(&offs[dst], 1);
    eids[pos] = e;
}

// ---------------- gather + output: out = sc + (Σ ex*v / Σ ex) @ W_lin2' ----------------
// one wave (64 lanes) per node: lane = eo*16+u processes edge-slot eo, component u
__global__ __launch_bounds__(256) void gather_out_kernel(
    const int* __restrict__ eids, const int* __restrict__ offs,
    const float* __restrict__ ex, const float* __restrict__ v_in,
    const float* __restrict__ sc, const float* __restrict__ W_lin2,
    float* __restrict__ out)
{
    __shared__ float sW[256];
    if (threadIdx.x < 256) sW[threadIdx.x] = W_lin2[threadIdx.x] * 0.25f;
    __syncthreads();

    int wave = threadIdx.x >> 6;
    int lane = threadIdx.x & 63;
    int n = blockIdx.x * 4 + wave;          // NN = 20000 = 5000*4, all full
    int u = lane & 15;
    int eo = lane >> 4;

    // after place_kernel, offs[n] = inclusive prefix; start = offs[n-1] (0 for n=0)
    int start = (n == 0) ? 0 : offs[n - 1];
    int end = offs[n];

    float accv = 0.f, accz = 0.f;
    for (int i = start + eo; i < end; i += 4) {
        int e = eids[i];
        float exv = ex[e];                       // broadcast across 16 lanes
        accv += exv * v_in[(size_t)e * 16 + u];  // 64B coalesced line per edge
        if (u == 0) accz += exv;
    }
    // reduce the 4 edge-slots (lanes differing in bits 4,5)
    accv += __shfl_xor(accv, 16);
    accv += __shfl_xor(accv, 32);
    accz += __shfl_xor(accz, 16);
    accz += __shfl_xor(accz, 32);
    float den = __shfl(accz, 0);
    float a = accv / (den == 0.f ? 1.f : den);   // lanes 0..15 hold a[u]

    if (lane < 16) {
        int c = lane;
        float t = sc[(size_t)n * 16 + c];
        #pragma unroll
        for (int uu = 0; uu < 16; ++uu) {
            float au = __shfl(a, uu);
            t += au * sW[uu * 16 + c];
        }
        out[(size_t)n * 16 + c] = t;
    }
}

} // namespace

extern "C" void kernel_launch(void* const* d_in, const int* in_sizes, int n_in,
                              void* d_out, int out_size, void* d_ws, size_t ws_size,
                              hipStream_t stream)
{
    const float* node_input   = (const float*)d_in[0];
    const float* node_attr    = (const float*)d_in[1];
    const int*   edge_src     = (const int*)d_in[2];
    const int*   edge_dst     = (const int*)d_in[3];
    const float* edge_attr    = (const float*)d_in[4];
    const float* edge_scalars = (const float*)d_in[5];
    const float* W_sc   = (const float*)d_in[6];
    const float* W_lin1 = (const float*)d_in[7];
    const float* W_hq   = (const float*)d_in[8];
    const float* fck_w0 = (const float*)d_in[9];
    const float* fck_w1 = (const float*)d_in[10];
    const float* fck_w2 = (const float*)d_in[11];
    const float* fck_w3 = (const float*)d_in[12];
    const float* fcv_w0 = (const float*)d_in[13];
    const float* fcv_w1 = (const float*)d_in[14];
    const float* fcv_w2 = (const float*)d_in[15];
    const float* fcv_w3 = (const float*)d_in[16];
    const float* W_dot  = (const float*)d_in[17];
    const float* W_lin2 = (const float*)d_in[18];

    float* ws  = (float*)d_ws;
    float* nf  = ws;                      // NN*16
    float* q   = nf  + (size_t)NN * 16;   // NN*8
    float* sc  = q   + (size_t)NN * 8;    // NN*16
    float* ex  = sc  + (size_t)NN * 16;   // NE
    float* vv  = ex  + NE;                // NE*16
    int*   counts = (int*)(vv + (size_t)NE * 16);  // NN
    int*   offs   = counts + NN;                   // NN
    int*   eids   = offs + NN;                     // NE

    hipMemsetAsync(counts, 0, (size_t)NN * sizeof(int), stream);

    node_kernel<<<(NN + 255) / 256, 256, 0, stream>>>(
        node_input, node_attr, W_sc, W_lin1, W_hq, nf, q, sc);
    edge_kernel<<<(NE + 255) / 256, 256, 0, stream>>>(
        nf, q, edge_src, edge_dst, edge_attr, edge_scalars,
        fck_w0, fck_w1, fck_w2, fck_w3, fcv_w0, fcv_w1, fcv_w2, fcv_w3,
        W_dot, ex, vv, counts);
    scan_kernel<<<1, 1024, 0, stream>>>(counts, offs);
    place_kernel<<<(NE + 255) / 256, 256, 0, stream>>>(edge_dst, offs, eids);
    gather_out_kernel<<<NN / 4, 256, 0, stream>>>(eids, offs, ex, vv, sc, W_lin2, (float*)d_out);
}